// Round 13
// baseline (184.567 us; speedup 1.0000x reference)
//
#include <hip/hip_runtime.h>
#include <hip/hip_bf16.h>

#define E_    8
#define CIN_  256
#define COUT_ 256
#define NK    9
#define KTOT  2304      // CIN*9
#define IMGH  56
#define IMGW  56
#define HW    3136
#define NBATCH 32
#define PADW  58
#define PADHW 3364      // 58*58

typedef __attribute__((ext_vector_type(8))) __bf16 bf16x8;
typedef __attribute__((ext_vector_type(4))) float f32x4;
typedef unsigned int u32;

// async global->LDS, 16B per lane; LDS dest = wave-uniform base + lane*16
__device__ __forceinline__ void gld_lds16(const __bf16* g, __bf16* l) {
    __builtin_amdgcn_global_load_lds(
        (const __attribute__((address_space(1))) void*)(g),
        (__attribute__((address_space(3))) void*)(l), 16, 0, 0);
}

// ---- init: pooled = 0, xTp halo = 0 ----
__global__ __launch_bounds__(256) void init_kernel(__bf16* xTp, float* pooled) {
    const int tid0 = blockIdx.x * 256 + threadIdx.x;
    if (tid0 < NBATCH * CIN_) pooled[tid0] = 0.f;
    const int total = NBATCH * 228 * 128;     // halo u32 count
    u32* p = (u32*)xTp;
    for (int idx = tid0; idx < total; idx += gridDim.x * 256) {
        const int n  = idx / (228 * 128);
        const int r  = idx - n * (228 * 128);
        const int hp = r >> 7;
        const int cp = r & 127;
        int px;
        if (hp < 58)       px = hp;
        else if (hp < 116) px = 57 * PADW + (hp - 58);
        else if (hp < 172) px = (hp - 116 + 1) * PADW;
        else               px = (hp - 172 + 1) * PADW + 57;
        p[((size_t)(n * PADHW + px)) * 128 + cp] = 0u;
    }
}

// ---- transpose + pool v2: block = 64 px x 256 cin; wide loads/stores ----
// Phase 1: float2 reads (8B/lane), LDS tile stored transposed [px][cin].
// Phase 2: u32 writes (2 bf16 = 4B/lane); 2 waves cover one px's 512B cin
// row -> 256B per store instruction. Pool partials folded into phase 2.
__global__ __launch_bounds__(256) void transpose_kernel(const float* __restrict__ x,
                                                        __bf16* __restrict__ xTp,
                                                        float* __restrict__ pooled) {
    __shared__ __bf16 t[64][258];             // 33 KB; 2-way max banks both sides
    const int px0 = blockIdx.x * 64;
    const int n   = blockIdx.y;
    const int tid = threadIdx.x;
    const int wave = tid >> 6;
    const int lane = tid & 63;

    // phase 1: read. round r: cin = r*8 + (tid>>5), px = 2*(tid&31)
    {
        const int cr  = tid >> 5;             // 0..7
        const int pxl = 2 * (tid & 31);
        const float* xp = x + ((size_t)(n * CIN_ + cr) * HW) + px0 + pxl;
        #pragma unroll
        for (int r = 0; r < 32; ++r) {
            const float2 v = *(const float2*)(xp + (size_t)(8 * r) * HW);
            t[pxl][r * 8 + cr]     = (__bf16)v.x;
            t[pxl + 1][r * 8 + cr] = (__bf16)v.y;
        }
    }
    __syncthreads();
    // phase 2: write + pool. round r: px = 2r + (wave>>1), u32 cin-pair
    // c = (wave&1)*64 + lane covering cins 2c, 2c+1.
    {
        const int c   = (wave & 1) * 64 + lane;   // u32 index: cins 2c,2c+1
        const int pxp = wave >> 1;                // px parity handled by wave
        float s0 = 0.f, s1 = 0.f;
        #pragma unroll
        for (int r = 0; r < 32; ++r) {
            const int pxl = 2 * r + pxp;
            const int pxg = px0 + pxl;
            const int h   = pxg / IMGW;
            const int w   = pxg - h * IMGW;
            const u32 v = *(const u32*)&t[pxl][2 * c];
            s0 += __uint_as_float(v << 16);
            s1 += __uint_as_float(v & 0xffff0000u);
            *(u32*)(xTp + ((size_t)(n * PADHW + (h + 1) * PADW + (w + 1))) * CIN_ + 2 * c) = v;
        }
        atomicAdd(&pooled[n * CIN_ + 2 * c], s0);
        atomicAdd(&pooled[n * CIN_ + 2 * c + 1], s1);
    }
}

// ---- mix (gate fused): block = (cout, n-chunk of 8); experts in registers --
__global__ __launch_bounds__(256) void mix_kernel(const float* __restrict__ weight,
                                                  const float* __restrict__ pooled,
                                                  const float* __restrict__ fc_w,
                                                  const float* __restrict__ fc_b,
                                                  __bf16* __restrict__ wmix) {
    __shared__ float wstage[KTOT];
    __shared__ __bf16 tlds[KTOT];
    __shared__ float gl[8][8];                // gate[n-local][e]
    const int cout = blockIdx.x;
    const int n0   = blockIdx.y * 8;
    const int tid  = threadIdx.x;
    // gate head: threads 0..63 each compute one (n-local, e) dot
    if (tid < 64) {
        const int nl = tid >> 3, e = tid & 7;
        const float* pv = pooled + (n0 + nl) * CIN_;
        const float* wv = fc_w + e * CIN_;
        float s = 0.f;
        for (int c = 0; c < CIN_; ++c) s += pv[c] * wv[c];
        s = s * (1.0f / HW) + fc_b[e];
        gl[nl][e] = 1.0f / (1.0f + expf(-s));
    }
    float wreg[E_][NK];
    for (int e = 0; e < E_; ++e) {
        const float* wp = weight + (size_t)(e * COUT_ + cout) * KTOT;
        #pragma unroll
        for (int i = 0; i < NK; ++i) wstage[tid + i * 256] = wp[tid + i * 256];
        __syncthreads();
        #pragma unroll
        for (int kk = 0; kk < NK; ++kk) wreg[e][kk] = wstage[tid * NK + kk];
        __syncthreads();
    }
    for (int n = n0; n < n0 + 8; ++n) {
        float g[E_];
        #pragma unroll
        for (int e = 0; e < E_; ++e) g[e] = gl[n - n0][e];
        float acc[NK];
        #pragma unroll
        for (int kk = 0; kk < NK; ++kk) acc[kk] = 0.f;
        #pragma unroll
        for (int e = 0; e < E_; ++e)
            #pragma unroll
            for (int kk = 0; kk < NK; ++kk) acc[kk] += g[e] * wreg[e][kk];
        #pragma unroll
        for (int kk = 0; kk < NK; ++kk) tlds[kk * 256 + tid] = (__bf16)acc[kk];
        __syncthreads();
        u32* dst = (u32*)(wmix + ((size_t)(n * COUT_ + cout)) * KTOT);
        const u32* src = (const u32*)tlds;
        #pragma unroll
        for (int j = 0; j < 4; ++j) dst[tid + j * 256] = src[tid + j * 256];
        if (tid < 128) dst[tid + 1024] = src[tid + 1024];
        __syncthreads();
    }
}

// ---------------- implicit-GEMM conv (r5/r10 structure, best measured) ----
// BM=256 couts x BN=224 pixels, 512 threads, 8 waves as 4M x 2N
// (wave tile 64x112 = 4x7 frags). 36 K-steps of 64, 2-buffer pipeline:
// STAGE(t+1) -> COMPUTE(t) -> __syncthreads (loads fly during compute,
// drain at the barrier). Proven 132 us / 37.5% MfmaUtil (r5, r10, r12).
#define BM 256
#define BN 224

__global__ __launch_bounds__(512) void conv_kernel(const __bf16* __restrict__ xTp,
                                                   const __bf16* __restrict__ wmix,
                                                   float* __restrict__ out) {
    __shared__ __attribute__((aligned(16))) __bf16 At[2][BM * 64];  // 2x32 KB
    __shared__ __attribute__((aligned(16))) __bf16 Bt[2][BN * 64];  // 2x28 KB

    // bijective XCD swizzle (448 = 8*56); n-major within XCD for L2 locality
    const int bid = blockIdx.x;
    const int swz = (bid & 7) * 56 + (bid >> 3);
    const int n   = swz / 14;
    const int pt  = swz - n * 14;
    const int p0  = pt * BN;

    const int tid  = threadIdx.x;
    const int lane = tid & 63;
    const int wave = tid >> 6;
    const int lr   = lane >> 3;               // row-within-chunk 0..7
    const int sl   = lane & 7;                // 16B slot within 128B row
    const int swzsl = sl ^ lr;                // pre-swizzled source slot

    const __bf16* wmixn = wmix + (size_t)n * COUT_ * KTOT;
    const __bf16* xTpn  = xTp + (size_t)n * PADHW * CIN_;

    // A staging: chunk j = wave+8i covers cout rows 8j..8j+7
    const __bf16* asrc[4];
    #pragma unroll
    for (int i = 0; i < 4; ++i) {
        const int j = wave + 8 * i;
        asrc[i] = wmixn + (size_t)(8 * j + lr) * KTOT + swzsl * 8;
    }
    // B staging: chunk j = wave+8i (j<28) covers pixel rows 8j..8j+7
    const __bf16* bsrc[4];
    #pragma unroll
    for (int i = 0; i < 4; ++i) {
        int j = wave + 8 * i; if (j > 27) j = 27;   // clamped, never issued
        const int px = p0 + 8 * j + lr;
        const int h  = px / IMGW;
        const int w  = px - h * IMGW;
        bsrc[i] = xTpn + (size_t)(h * PADW + w) * CIN_ + swzsl * 8;
    }

    const f32x4 zero = {0.f, 0.f, 0.f, 0.f};
    f32x4 acc[4][7];
    #pragma unroll
    for (int i = 0; i < 4; ++i)
        #pragma unroll
        for (int j = 0; j < 7; ++j) acc[i][j] = zero;

    const int mbase = (wave >> 1) * 64;
    const int nbase = (wave & 1) * 112;
    const int fr = lane & 15;
    const int kg = lane >> 4;
    const int fswz = fr & 7;

    auto STAGE = [&](int buf, int stepk, int toff) {
        #pragma unroll
        for (int i = 0; i < 4; ++i)
            gld_lds16(asrc[i] + stepk * 64, &At[buf][(wave + 8 * i) * 512]);
        const int boff = toff * 256 + (stepk & 3) * 64;
        #pragma unroll
        for (int i = 0; i < 4; ++i)
            if (wave < 4 || i < 3)
                gld_lds16(bsrc[i] + boff, &Bt[buf][(wave + 8 * i) * 512]);
    };

    auto COMPUTE = [&](const __bf16* Ab, const __bf16* Bb) {
        #pragma unroll
        for (int ks = 0; ks < 2; ++ks) {
            const int soff = ((ks * 4 + kg) ^ fswz) * 8;
            bf16x8 a[4], b[7];
            #pragma unroll
            for (int m = 0; m < 4; ++m)
                a[m] = *(const bf16x8*)(Ab + (mbase + m * 16 + fr) * 64 + soff);
            #pragma unroll
            for (int nn = 0; nn < 7; ++nn)
                b[nn] = *(const bf16x8*)(Bb + (nbase + nn * 16 + fr) * 64 + soff);
            #pragma unroll
            for (int m = 0; m < 4; ++m)
                #pragma unroll
                for (int nn = 0; nn < 7; ++nn)
                    acc[m][nn] = __builtin_amdgcn_mfma_f32_16x16x32_bf16(
                        a[m], b[nn], acc[m][nn], 0, 0, 0);
        }
    };

    STAGE(0, 0, 0);
    __syncthreads();
    for (int khw = 0; khw < 9; ++khw) {
        const int kh  = (khw * 11) >> 5;          // khw/3
        const int kw  = khw - kh * 3;
        const int toff = kh * PADW + kw;
        const int kh2 = ((khw + 1) * 11) >> 5;    // (khw+1)/3
        const int kw2 = (khw + 1) - kh2 * 3;
        const int toff2 = kh2 * PADW + kw2;
        #pragma unroll
        for (int cb = 0; cb < 4; ++cb) {
            const int buf  = cb & 1;
            const int step = khw * 4 + cb;
            if (step < 35)
                STAGE(buf ^ 1, step + 1, (cb < 3) ? toff : toff2);
            COMPUTE(&At[buf][0], &Bt[buf][0]);
            __syncthreads();
        }
    }

    // epilogue: D col = lane&15 (pixel), row = (lane>>4)*4 + reg (cout)
    const int rbase = kg * 4;
    #pragma unroll
    for (int m = 0; m < 4; ++m)
        #pragma unroll
        for (int nn = 0; nn < 7; ++nn) {
            float* op = out + (size_t)(n * COUT_ + mbase + m * 16 + rbase) * HW
                            + p0 + nbase + nn * 16 + fr;
            #pragma unroll
            for (int r = 0; r < 4; ++r)
                op[(size_t)r * HW] = acc[m][nn][r];
        }
}

extern "C" void kernel_launch(void* const* d_in, const int* in_sizes, int n_in,
                              void* d_out, int out_size, void* d_ws, size_t ws_size,
                              hipStream_t stream) {
    const float* x      = (const float*)d_in[0];
    const float* weight = (const float*)d_in[1];
    const float* fc_w   = (const float*)d_in[2];
    const float* fc_b   = (const float*)d_in[3];
    float* out = (float*)d_out;

    // workspace layout (~92.9 MB)
    char* ws = (char*)d_ws;
    float* pooled = (float*)ws;                                   // 32 KB
    __bf16* wmix  = (__bf16*)(ws + 64 * 1024);                    // 37.75 MB
    __bf16* xTp   = (__bf16*)(ws + 64 * 1024 +
                              (size_t)NBATCH * COUT_ * KTOT * 2); // 55.1 MB

    init_kernel<<<dim3(512), 256, 0, stream>>>(xTp, pooled);
    transpose_kernel<<<dim3(49, NBATCH), 256, 0, stream>>>(x, xTp, pooled);
    mix_kernel<<<dim3(COUT_, 4), 256, 0, stream>>>(weight, pooled, fc_w, fc_b, wmix);
    conv_kernel<<<dim3(448), 512, 0, stream>>>(xTp, wmix, out);
}